// Round 8
// baseline (96.420 us; speedup 1.0000x reference)
//
#include <hip/hip_runtime.h>
#include <hip/hip_bf16.h>
#include <math.h>

// SelfRetentionV1: B=2,H=16,L=2048,DK=128,DV=128
// out[b,l,h,d] = RMSNorm_d( (QK^T * gamma^(i-j) / max(1,|rowsum|)) @ V )
#define B_ 2
#define H_ 16
#define L_ 2048
#define DK_ 128
#define DV_ 128
#define QBLK 64
#define KVBLK 64
#define NIT (L_/KVBLK)   // 32

typedef __bf16 bf16x8 __attribute__((ext_vector_type(8)));
typedef float  f32x16 __attribute__((ext_vector_type(16)));

static __device__ __forceinline__ unsigned short f2bf(float f) {
    union { float f; unsigned int u; } x; x.f = f;
    unsigned int r = x.u + 0x7fffu + ((x.u >> 16) & 1u);  // RNE
    return (unsigned short)(r >> 16);
}

// async global->LDS, 16B per lane; LDS dest = wave-uniform base + lane*16
static __device__ __forceinline__ void gload_lds16(const void* g, void* l) {
    __builtin_amdgcn_global_load_lds(
        (const __attribute__((address_space(1))) unsigned int*)g,
        (__attribute__((address_space(3))) unsigned int*)l,
        16, 0, 0);
}

// K tile rows are 256B: swizzle bits 4-6 by row&7 (involution, row bits >=8)
#define KSWZ(d) ((d) ^ ((((d) >> 8) & 7) << 4))
// V tile rows are 128B: row bits >=7
#define VSWZ(d) ((d) ^ ((((d) >> 7) & 7) << 4))

// ---- fused pre-pass: blocks 0..1023 convert K fp32->bf16;
//      blocks 1024..2047 transpose V -> VT[bh][dv][perm(l)] (bit2<->3 perm
//      so P-register order == mfma k-slot order in PV) ----
__global__ void prep_kernel(const float* __restrict__ kin,
                            unsigned short* __restrict__ kb,
                            const float* __restrict__ v,
                            unsigned short* __restrict__ vt) {
    __shared__ unsigned short lds[64][130];   // +2 pad (transpose half only)
    int bid = blockIdx.x;
    if (bid < 1024) {
        int n4 = B_ * H_ * L_ * DK_ / 4;
        int i = bid * 256 + threadIdx.x;
        int stride = 1024 * 256;
        for (; i < n4; i += stride) {
            float4 f = ((const float4*)kin)[i];
            uint2 o;
            o.x = (unsigned)f2bf(f.x) | ((unsigned)f2bf(f.y) << 16);
            o.y = (unsigned)f2bf(f.z) | ((unsigned)f2bf(f.w) << 16);
            ((uint2*)kb)[i] = o;
        }
        return;
    }
    int blk = bid - 1024;
    int ltile = blk & (L_/64 - 1);
    int bh = blk / (L_/64);
    const float* vp = v + ((size_t)bh * L_ + (size_t)ltile * 64) * DV_;
    unsigned short* vo = vt + (size_t)bh * DV_ * L_ + ltile * 64;
    int t = threadIdx.x;
    int r0 = t >> 5, c0 = (t & 31) * 4;
    #pragma unroll
    for (int it = 0; it < 8; ++it) {
        int row = r0 + 8 * it;
        float4 f = *(const float4*)(vp + row * DV_ + c0);
        lds[row][c0 + 0] = f2bf(f.x);
        lds[row][c0 + 1] = f2bf(f.y);
        lds[row][c0 + 2] = f2bf(f.z);
        lds[row][c0 + 3] = f2bf(f.w);
    }
    __syncthreads();
    int dvb = t >> 3, seg = t & 7;
    #pragma unroll
    for (int ot = 0; ot < 4; ++ot) {
        int dv = dvb + 32 * ot;
        unsigned short a[8];
        #pragma unroll
        for (int tt = 0; tt < 8; ++tt) {
            int pp = seg * 8 + tt;
            int js = (pp & ~12) | ((pp & 4) << 1) | ((pp & 8) >> 1);  // swap b2,b3
            a[tt] = lds[js][dv];
        }
        uint4 st;
        st.x = (unsigned)a[0] | ((unsigned)a[1] << 16);
        st.y = (unsigned)a[2] | ((unsigned)a[3] << 16);
        st.z = (unsigned)a[4] | ((unsigned)a[5] << 16);
        st.w = (unsigned)a[6] | ((unsigned)a[7] << 16);
        *(uint4*)(vo + (size_t)dv * L_ + seg * 8) = st;
    }
}

// ---- main kernel: 4 waves (rh,kh); swapped QK^T, register P.
// Asymmetric prefetch: K TRI-buffered, staged 2 rounds ahead (needed early);
// V double-buffered, staged post-barrier 1 round ahead (needed late).
// One counted vmcnt + one s_barrier per round; waits never drain the
// freshest K stage.
// Ledger: K(t+2)->kbuf[(t+2)%3], last readers QK(t-1) < barrier(t-1) < issue.
//         V(t+1)->vbuf[(t+1)&1], last readers PV(t-1) < QK(t) < barrier(t)
//         < issue. QK(t) reads K(t): drained by vmcnt@t-1 (leaves only
//         K(t+1)... wait leaves K(t+2-1)?  -- at round t-1 the wait leaves
//         only K(t+1), so K(t) drained; published by barrier(t-1).
//         PV(t) reads V(t): V(t) older than K(t+2) => drained by vmcnt@t,
//         published by barrier(t).
__launch_bounds__(256, 2)
__global__ void retention_kernel(const float* __restrict__ q,
                                 const unsigned short* __restrict__ kb,
                                 const unsigned short* __restrict__ vt_,
                                 float* __restrict__ out) {
    __shared__ __align__(16) unsigned short kbuf[3][64 * 128];   // 48 KB
    __shared__ __align__(16) unsigned short vbuf[2][128 * 64];   // 32 KB

    // bh->XCD-pinned remap (xcd = bid%8): 4 bh per XCD -> ~4MB K+V ~= L2
    int bid = blockIdx.x;
    int x    = bid & 7;
    int t_   = bid >> 3;
    int slot = t_ & 31;
    int hi   = t_ >> 5;
    int itile = (hi & 1) ? (31 - slot) : slot;
    int bh = hi * 8 + x;
    int b = bh >> 4, h = bh & 15;

    int tid = threadIdx.x;
    int lane = tid & 63;
    int w = tid >> 6;                   // 0..3
    int rh = w >> 1;                    // q-row half
    int kh = w & 1;                     // kv half
    int il = lane & 31;
    int hl = lane >> 5;

    int i_base = itile * QBLK + rh * 32;
    int i_row  = i_base + il;           // this lane's q-row

    const unsigned short* kbp = kb  + (size_t)bh * L_ * DK_;
    const unsigned short* vtp = vt_ + (size_t)bh * DV_ * L_;

    // ---- prologue staging: K(0), V(0), K(1) ----
    {
        const char* ksrc = (const char*)kbp;
        const char* vsrc = (const char*)vtp;
        #pragma unroll
        for (int is = 0; is < 4; ++is) {
            int dw = is * 4096 + w * 1024;
            int d  = dw + lane * 16;
            gload_lds16(ksrc + KSWZ(d), (char*)&kbuf[0][0] + dw);
        }
        #pragma unroll
        for (int is = 0; is < 4; ++is) {
            int dw = is * 4096 + w * 1024;
            int d  = dw + lane * 16;
            int sv = VSWZ(d);
            gload_lds16(vsrc + (size_t)(sv >> 7) * (L_ * 2) + (sv & 127),
                        (char*)&vbuf[0][0] + dw);
        }
        if (itile >= 1) {
            const char* k1 = (const char*)(kbp + (size_t)KVBLK * DK_);
            #pragma unroll
            for (int is = 0; is < 4; ++is) {
                int dw = is * 4096 + w * 1024;
                int d  = dw + lane * 16;
                gload_lds16(k1 + KSWZ(d), (char*)&kbuf[1][0] + dw);
            }
        }
    }

    float ex = exp2f((float)(-5 - h));
    float gamma = 1.0f - ex;
    float log2g = log1pf(-ex) * 1.44269504088896f;

    // colfac[r] = gamma^(-jr), jr = (r&3) + 8*(r>>2) + 4*hl
    float gi  = exp2f(-log2g);
    float gi2 = gi * gi, gi3 = gi2 * gi, gi4 = gi2 * gi2;
    float gi8 = gi4 * gi4, gi16 = gi8 * gi8, gi24 = gi16 * gi8;
    float cfq[4] = {1.f, gi, gi2, gi3};
    float cfp[4] = {1.f, gi8, gi16, gi24};
    float chl = hl ? gi4 : 1.f;
    float colfac[16];
    #pragma unroll
    for (int r = 0; r < 16; ++r) colfac[r] = cfq[r & 3] * cfp[r >> 2] * chl;

    // arow = gamma^(i - jt*64 - kh*32), advanced by *= gamma^-64 per tile
    float arow = exp2f(log2g * (float)(i_row - kh * 32));
    float gm64i = exp2f(log2g * (-64.0f));
    int icmp = rh * 32 + il - kh * 32;   // diag mask: jr <= icmp

    // Q as B-operand: col = il (q-row i_row), k = ks*16 + hl*8 + 0..7
    bf16x8 qf[8];
    {
        const float* qp = q + ((size_t)bh * L_ + i_row) * DK_ + hl * 8;
        #pragma unroll
        for (int ks = 0; ks < 8; ++ks) {
            float4 f0 = *(const float4*)(qp + ks * 16);
            float4 f1 = *(const float4*)(qp + ks * 16 + 4);
            union { bf16x8 v; unsigned short u[8]; } A;
            A.u[0]=f2bf(f0.x); A.u[1]=f2bf(f0.y); A.u[2]=f2bf(f0.z); A.u[3]=f2bf(f0.w);
            A.u[4]=f2bf(f1.x); A.u[5]=f2bf(f1.y); A.u[6]=f2bf(f1.z); A.u[7]=f2bf(f1.w);
            qf[ks] = A.v;
        }
    }

    f32x16 o[4];                        // O^T: lane = dv (il), regs = i-pattern
    #pragma unroll
    for (int nt = 0; nt < 4; ++nt)
        #pragma unroll
        for (int e = 0; e < 16; ++e) o[nt][e] = 0.0f;
    float rowsum = 0.0f;

    int rswz = (il & 7) << 4;           // read-side XOR (rows == il mod 8)
    int krow256 = (kh * 32 + il) * 256;
    int hl16 = hl * 16;

    // prologue drain: K(0),V(0) done; leave K(1) in flight
    if (itile >= 1) asm volatile("s_waitcnt vmcnt(4)" ::: "memory");
    else            asm volatile("s_waitcnt vmcnt(0)" ::: "memory");
    asm volatile("s_barrier" ::: "memory");

    int kr = 0;                          // kbuf slot holding K(jt)
    for (int jt = 0; jt <= itile; ++jt) {
        // ---- stage K(jt+2) two rounds ahead (overwrite guarded by barrier(t-1))
        if (jt + 2 <= itile) {
            int ks2 = kr + 2; if (ks2 >= 3) ks2 -= 3;
            const char* ksrc = (const char*)(kbp + (size_t)(jt + 2) * KVBLK * DK_);
            char* kdst = (char*)&kbuf[ks2][0];
            #pragma unroll
            for (int is = 0; is < 4; ++is) {
                int dw = is * 4096 + w * 1024;
                int d  = dw + lane * 16;
                gload_lds16(ksrc + KSWZ(d), kdst + dw);
            }
        }

        const char* kb_c = (const char*)&kbuf[kr][0];

        // ---- S^T = mfma(K, Q): lane = i, regs = j (swapped operands) ----
        f32x16 s;
        #pragma unroll
        for (int e = 0; e < 16; ++e) s[e] = 0.0f;
        #pragma unroll
        for (int ks = 0; ks < 8; ++ks) {
            bf16x8 kf = *(const bf16x8*)(kb_c + krow256 + ((ks * 32 + hl16) ^ rswz));
            s = __builtin_amdgcn_mfma_f32_32x32x16_bf16(kf, qf[ks], s, 0, 0, 0);
        }

        // ---- decay + (diag) mask + rowsum + pack P (native bf16 casts) ----
        float ab = arow;
        arow *= gm64i;
        float val[16];
        if (jt == itile) {
            #pragma unroll
            for (int r = 0; r < 16; ++r) {
                int jr = (r & 3) + 8 * (r >> 2) + 4 * hl;
                float vv = s[r] * (colfac[r] * ab);
                vv = (jr <= icmp) ? vv : 0.0f;
                rowsum += vv;
                val[r] = vv;
            }
        } else {
            #pragma unroll
            for (int r = 0; r < 16; ++r) {
                float vv = s[r] * (colfac[r] * ab);
                rowsum += vv;
                val[r] = vv;
            }
        }
        union { bf16x8 v; __bf16 e[8]; } P0, P1;
        #pragma unroll
        for (int e = 0; e < 8; ++e) { P0.e[e] = (__bf16)val[e]; P1.e[e] = (__bf16)val[8 + e]; }

        // ---- counted drain: V(jt) (and K(jt+1), older) done; K(jt+2) stays
        if (jt + 2 <= itile) asm volatile("s_waitcnt vmcnt(4)" ::: "memory");
        else                 asm volatile("s_waitcnt vmcnt(0)" ::: "memory");
        asm volatile("s_barrier" ::: "memory");

        // ---- stage V(jt+1) post-barrier (all waves done PV(jt-1)) ----
        if (jt + 1 <= itile) {
            const char* vsrc = (const char*)(vtp + (jt + 1) * KVBLK);
            char* vdst = (char*)&vbuf[(jt + 1) & 1][0];
            #pragma unroll
            for (int is = 0; is < 4; ++is) {
                int dw = is * 4096 + w * 1024;
                int d  = dw + lane * 16;
                int sv = VSWZ(d);
                gload_lds16(vsrc + (size_t)(sv >> 7) * (L_ * 2) + (sv & 127), vdst + dw);
            }
        }

        // ---- O^T += mfma(P, V_perm) from vbuf[jt&1] ----
        {
            const char* vb_c = (const char*)&vbuf[jt & 1][0];
            #pragma unroll
            for (int nt = 0; nt < 4; ++nt) {
                bf16x8 vb0 = *(const bf16x8*)(vb_c + (nt * 32 + il) * 128
                                              + ((kh * 64 + hl16) ^ rswz));
                o[nt] = __builtin_amdgcn_mfma_f32_32x32x16_bf16(P0.v, vb0, o[nt], 0, 0, 0);
                bf16x8 vb1 = *(const bf16x8*)(vb_c + (nt * 32 + il) * 128
                                              + ((kh * 64 + 32 + hl16) ^ rswz));
                o[nt] = __builtin_amdgcn_mfma_f32_32x32x16_bf16(P1.v, vb1, o[nt], 0, 0, 0);
            }
        }

        kr = (kr == 2) ? 0 : kr + 1;
    }

    // ---- rowsum: combine hl halves (each holds 16 of the wave's 32 j's) ----
    float rsw = rowsum + __shfl_xor(rowsum, 32);

    // ---- cross-kh reduction via LDS (buffers dead now) ----
    __syncthreads();   // all tile reads done before buffer reuse
    float* exch = (float*)&kbuf[0][0];       // 32 KB: rh pairs at +rh*4096 floats
    float* rsx  = (float*)&vbuf[0][0];
    if (kh == 1) {
        float* eb = exch + rh * 4096;
        #pragma unroll
        for (int nt = 0; nt < 4; ++nt)
            #pragma unroll
            for (int qq = 0; qq < 4; ++qq) {
                float4 vv = { o[nt][4*qq+0], o[nt][4*qq+1],
                              o[nt][4*qq+2], o[nt][4*qq+3] };
                *(float4*)(eb + (nt * 4 + qq) * 256 + lane * 4) = vv;
            }
        if (lane < 32) rsx[rh * 32 + lane] = rsw;
    }
    __syncthreads();
    if (kh == 0) {
        float* eb = exch + rh * 4096;
        #pragma unroll
        for (int nt = 0; nt < 4; ++nt)
            #pragma unroll
            for (int qq = 0; qq < 4; ++qq) {
                float4 pv = *(const float4*)(eb + (nt * 4 + qq) * 256 + lane * 4);
                o[nt][4*qq+0] += pv.x; o[nt][4*qq+1] += pv.y;
                o[nt][4*qq+2] += pv.z; o[nt][4*qq+3] += pv.w;
            }
        float rtot = rsw + rsx[rh * 32 + il];
        float dnl = 1.0f / fmaxf(1.0f, fabsf(rtot));   // lane L&31 holds row L&31

        #pragma unroll
        for (int r = 0; r < 16; ++r) {
            int isrc = (r & 3) + 8 * (r >> 2) + 4 * hl;   // i_local of reg r
            float dn = __shfl(dnl, isrc);
            float ov[4];
            float ss = 0.0f;
            #pragma unroll
            for (int nt = 0; nt < 4; ++nt) { ov[nt] = o[nt][r] * dn; ss += ov[nt] * ov[nt]; }
            ss += __shfl_xor(ss, 1);
            ss += __shfl_xor(ss, 2);
            ss += __shfl_xor(ss, 4);
            ss += __shfl_xor(ss, 8);
            ss += __shfl_xor(ss, 16);
            float sc = rsqrtf(ss * (1.0f / 128.0f) + 1e-6f);
            int i_abs = i_base + isrc;
            float* op = out + (((size_t)b * L_ + i_abs) * H_ + h) * DV_ + il;
            #pragma unroll
            for (int nt = 0; nt < 4; ++nt) op[nt * 32] = ov[nt] * sc;
        }
    }
}

// ---- fp32 fixup for row i=0 (single-term row: eps-magnified bf16 error) ----
__global__ void fix_row0_kernel(const float* __restrict__ q,
                                const float* __restrict__ k,
                                const float* __restrict__ v,
                                float* __restrict__ out) {
    int bh = blockIdx.x;            // 0..31
    int lane = threadIdx.x;         // 0..63
    const float* qp = q + (size_t)bh * L_ * DK_;
    const float* kp = k + (size_t)bh * L_ * DK_;
    const float* vp = v + (size_t)bh * L_ * DV_;
    float part = qp[lane] * kp[lane] + qp[lane + 64] * kp[lane + 64];
    #pragma unroll
    for (int mm = 1; mm < 64; mm <<= 1) part += __shfl_xor(part, mm);
    float r00 = part;
    float cf = r00 / fmaxf(1.0f, fabsf(r00));
    float o0 = cf * vp[lane], o1 = cf * vp[lane + 64];
    float ss = o0 * o0 + o1 * o1;
    #pragma unroll
    for (int mm = 1; mm < 64; mm <<= 1) ss += __shfl_xor(ss, mm);
    float sc = rsqrtf(ss * (1.0f / 128.0f) + 1e-6f);
    int b = bh >> 4, h = bh & 15;
    float* op = out + ((size_t)b * L_ * H_ + h) * DV_;   // i = 0
    op[lane] = o0 * sc;
    op[lane + 64] = o1 * sc;
}

extern "C" void kernel_launch(void* const* d_in, const int* in_sizes, int n_in,
                              void* d_out, int out_size, void* d_ws, size_t ws_size,
                              hipStream_t stream) {
    const float* q = (const float*)d_in[0];
    const float* k = (const float*)d_in[1];
    const float* v = (const float*)d_in[2];
    // d_in[3] decay_mask (256MB) and d_in[4] intra_decay are recomputed on the fly
    float* out = (float*)d_out;

    unsigned short* kb = (unsigned short*)d_ws;                 // 16 MB
    unsigned short* vt = kb + (size_t)B_ * H_ * L_ * DK_;       // 16 MB

    prep_kernel<<<2048, 256, 0, stream>>>(k, kb, v, vt);
    retention_kernel<<<B_ * H_ * NIT, 256, 0, stream>>>(q, kb, vt, out);
    fix_row0_kernel<<<B_ * H_, 64, 0, stream>>>(q, k, v, out);
}

// Round 9
// 88.976 us; speedup vs baseline: 1.0837x; 1.0837x over previous
//
#include <hip/hip_runtime.h>
#include <hip/hip_bf16.h>
#include <math.h>

// SelfRetentionV1: B=2,H=16,L=2048,DK=128,DV=128
// out[b,l,h,d] = RMSNorm_d( (QK^T * gamma^(i-j) / max(1,|rowsum|)) @ V )
#define B_ 2
#define H_ 16
#define L_ 2048
#define DK_ 128
#define DV_ 128
#define QBLK 64
#define KVBLK 64
#define NIT (L_/KVBLK)   // 32

typedef __bf16 bf16x8 __attribute__((ext_vector_type(8)));
typedef float  f32x16 __attribute__((ext_vector_type(16)));

static __device__ __forceinline__ unsigned short f2bf(float f) {
    union { float f; unsigned int u; } x; x.f = f;
    unsigned int r = x.u + 0x7fffu + ((x.u >> 16) & 1u);  // RNE
    return (unsigned short)(r >> 16);
}

// async global->LDS, 16B per lane; LDS dest = wave-uniform base + lane*16
static __device__ __forceinline__ void gload_lds16(const void* g, void* l) {
    __builtin_amdgcn_global_load_lds(
        (const __attribute__((address_space(1))) unsigned int*)g,
        (__attribute__((address_space(3))) unsigned int*)l,
        16, 0, 0);
}

// K tile rows are 256B: swizzle bits 4-6 by row&7 (involution, row bits >=8)
#define KSWZ(d) ((d) ^ ((((d) >> 8) & 7) << 4))
// V tile rows are 128B: row bits >=7
#define VSWZ(d) ((d) ^ ((((d) >> 7) & 7) << 4))

// ---- fused pre-pass: blocks 0..1023 convert K fp32->bf16;
//      blocks 1024..2047 transpose V -> VT[bh][dv][perm(l)] (bit2<->3 perm
//      so P-register order == mfma k-slot order in PV) ----
__global__ void prep_kernel(const float* __restrict__ kin,
                            unsigned short* __restrict__ kb,
                            const float* __restrict__ v,
                            unsigned short* __restrict__ vt) {
    __shared__ unsigned short lds[64][130];   // +2 pad (transpose half only)
    int bid = blockIdx.x;
    if (bid < 1024) {
        int n4 = B_ * H_ * L_ * DK_ / 4;
        int i = bid * 256 + threadIdx.x;
        int stride = 1024 * 256;
        for (; i < n4; i += stride) {
            float4 f = ((const float4*)kin)[i];
            uint2 o;
            o.x = (unsigned)f2bf(f.x) | ((unsigned)f2bf(f.y) << 16);
            o.y = (unsigned)f2bf(f.z) | ((unsigned)f2bf(f.w) << 16);
            ((uint2*)kb)[i] = o;
        }
        return;
    }
    int blk = bid - 1024;
    int ltile = blk & (L_/64 - 1);
    int bh = blk / (L_/64);
    const float* vp = v + ((size_t)bh * L_ + (size_t)ltile * 64) * DV_;
    unsigned short* vo = vt + (size_t)bh * DV_ * L_ + ltile * 64;
    int t = threadIdx.x;
    int r0 = t >> 5, c0 = (t & 31) * 4;
    #pragma unroll
    for (int it = 0; it < 8; ++it) {
        int row = r0 + 8 * it;
        float4 f = *(const float4*)(vp + row * DV_ + c0);
        lds[row][c0 + 0] = f2bf(f.x);
        lds[row][c0 + 1] = f2bf(f.y);
        lds[row][c0 + 2] = f2bf(f.z);
        lds[row][c0 + 3] = f2bf(f.w);
    }
    __syncthreads();
    int dvb = t >> 3, seg = t & 7;
    #pragma unroll
    for (int ot = 0; ot < 4; ++ot) {
        int dv = dvb + 32 * ot;
        unsigned short a[8];
        #pragma unroll
        for (int tt = 0; tt < 8; ++tt) {
            int pp = seg * 8 + tt;
            int js = (pp & ~12) | ((pp & 4) << 1) | ((pp & 8) >> 1);  // swap b2,b3
            a[tt] = lds[js][dv];
        }
        uint4 st;
        st.x = (unsigned)a[0] | ((unsigned)a[1] << 16);
        st.y = (unsigned)a[2] | ((unsigned)a[3] << 16);
        st.z = (unsigned)a[4] | ((unsigned)a[5] << 16);
        st.w = (unsigned)a[6] | ((unsigned)a[7] << 16);
        *(uint4*)(vo + (size_t)dv * L_ + seg * 8) = st;
    }
}

// ---- main kernel: 4 waves (rh,kh); swapped QK^T, register P.
// Structure = the proven 89.3us kernel (K/V dbuf, stage-at-top, vmcnt(8),
// 2 s_barrier/round). This round: dependency surgery only --
// QK split into 2 accumulator chains; PV half-0 issued between the two
// decay/pack halves (MFMA || VALU overlap); tree rowsum; hoisted stage addrs.
__launch_bounds__(256, 2)
__global__ void retention_kernel(const float* __restrict__ q,
                                 const unsigned short* __restrict__ kb,
                                 const unsigned short* __restrict__ vt_,
                                 float* __restrict__ out) {
    __shared__ __align__(16) unsigned short kbuf[2][64 * 128];   // 32 KB
    __shared__ __align__(16) unsigned short vbuf[2][128 * 64];   // 32 KB

    // bh->XCD-pinned remap (xcd = bid%8): 4 bh per XCD -> ~4MB K+V ~= L2
    int bid = blockIdx.x;
    int x    = bid & 7;
    int t_   = bid >> 3;
    int slot = t_ & 31;
    int hi   = t_ >> 5;
    int itile = (hi & 1) ? (31 - slot) : slot;
    int bh = hi * 8 + x;
    int b = bh >> 4, h = bh & 15;

    int tid = threadIdx.x;
    int lane = tid & 63;
    int w = tid >> 6;                   // 0..3
    int rh = w >> 1;                    // q-row half
    int kh = w & 1;                     // kv half
    int il = lane & 31;
    int hl = lane >> 5;

    int i_base = itile * QBLK + rh * 32;
    int i_row  = i_base + il;           // this lane's q-row

    const unsigned short* kbp = kb  + (size_t)bh * L_ * DK_;
    const unsigned short* vtp = vt_ + (size_t)bh * DV_ * L_;

    // hoisted per-lane stage offsets (loop-invariant)
    int dwv[4], koff[4], voff[4];
    #pragma unroll
    for (int is = 0; is < 4; ++is) {
        int dw = is * 4096 + w * 1024;
        int d  = dw + lane * 16;
        dwv[is]  = dw;
        koff[is] = KSWZ(d);
        int sv   = VSWZ(d);
        voff[is] = (sv >> 7) * (L_ * 2) + (sv & 127);
    }

    // ---- stage tile 0 (DMA runs under setup below) ----
    {
        const char* ksrc = (const char*)kbp;
        const char* vsrc = (const char*)vtp;
        #pragma unroll
        for (int is = 0; is < 4; ++is) {
            gload_lds16(ksrc + koff[is], (char*)&kbuf[0][0] + dwv[is]);
            gload_lds16(vsrc + voff[is], (char*)&vbuf[0][0] + dwv[is]);
        }
    }

    float ex = exp2f((float)(-5 - h));
    float gamma = 1.0f - ex;
    float log2g = log1pf(-ex) * 1.44269504088896f;

    // colfac[r] = gamma^(-jr), jr = (r&3) + 8*(r>>2) + 4*hl
    float gi  = exp2f(-log2g);
    float gi2 = gi * gi, gi3 = gi2 * gi, gi4 = gi2 * gi2;
    float gi8 = gi4 * gi4, gi16 = gi8 * gi8, gi24 = gi16 * gi8;
    float cfq[4] = {1.f, gi, gi2, gi3};
    float cfp[4] = {1.f, gi8, gi16, gi24};
    float chl = hl ? gi4 : 1.f;
    float colfac[16];
    #pragma unroll
    for (int r = 0; r < 16; ++r) colfac[r] = cfq[r & 3] * cfp[r >> 2] * chl;

    // arow = gamma^(i - jt*64 - kh*32), advanced by *= gamma^-64 per tile
    float arow = exp2f(log2g * (float)(i_row - kh * 32));
    float gm64i = exp2f(log2g * (-64.0f));
    int icmp = rh * 32 + il - kh * 32;   // diag mask: jr <= icmp
    unsigned mbits = 0;                  // bit r: keep reg r on diagonal tile
    #pragma unroll
    for (int r = 0; r < 16; ++r)
        if (((r & 3) + 8 * (r >> 2) + 4 * hl) <= icmp) mbits |= 1u << r;

    // Q as B-operand: col = il (q-row i_row), k = ks*16 + hl*8 + 0..7
    bf16x8 qf[8];
    {
        const float* qp = q + ((size_t)bh * L_ + i_row) * DK_ + hl * 8;
        #pragma unroll
        for (int ks = 0; ks < 8; ++ks) {
            float4 f0 = *(const float4*)(qp + ks * 16);
            float4 f1 = *(const float4*)(qp + ks * 16 + 4);
            union { bf16x8 v; unsigned short u[8]; } A;
            A.u[0]=f2bf(f0.x); A.u[1]=f2bf(f0.y); A.u[2]=f2bf(f0.z); A.u[3]=f2bf(f0.w);
            A.u[4]=f2bf(f1.x); A.u[5]=f2bf(f1.y); A.u[6]=f2bf(f1.z); A.u[7]=f2bf(f1.w);
            qf[ks] = A.v;
        }
    }

    f32x16 o[4];                        // O^T: lane = dv (il), regs = i-pattern
    #pragma unroll
    for (int nt = 0; nt < 4; ++nt)
        #pragma unroll
        for (int e = 0; e < 16; ++e) o[nt][e] = 0.0f;
    float rowsum = 0.0f;

    int rswz = (il & 7) << 4;           // read-side XOR (rows == il mod 8)
    int krow256 = (kh * 32 + il) * 256;
    int hl16 = hl * 16;

    int cur = 0;
    for (int jt = 0; jt <= itile; ++jt) {
        // issue next stage, then wait for PREVIOUS stage only (counted vmcnt)
        if (jt < itile) {
            const char* ksrc = (const char*)(kbp + (size_t)(jt + 1) * KVBLK * DK_);
            const char* vsrc = (const char*)(vtp + (jt + 1) * KVBLK);
            char* kdst = (char*)&kbuf[cur ^ 1][0];
            char* vdst = (char*)&vbuf[cur ^ 1][0];
            #pragma unroll
            for (int is = 0; is < 4; ++is) {
                gload_lds16(ksrc + koff[is], kdst + dwv[is]);
                gload_lds16(vsrc + voff[is], vdst + dwv[is]);
            }
            asm volatile("s_waitcnt vmcnt(8)" ::: "memory");
        } else {
            asm volatile("s_waitcnt vmcnt(0)" ::: "memory");
        }
        asm volatile("s_barrier" ::: "memory");   // all waves' stage(jt) landed

        const char* kb_c = (const char*)&kbuf[cur][0];
        const char* vb_c = (const char*)&vbuf[cur][0];

        // ---- S^T = mfma(K, Q): TWO independent 4-deep chains ----
        f32x16 sa, sb;
        #pragma unroll
        for (int e = 0; e < 16; ++e) { sa[e] = 0.0f; sb[e] = 0.0f; }
        #pragma unroll
        for (int ks = 0; ks < 4; ++ks) {
            bf16x8 kf0 = *(const bf16x8*)(kb_c + krow256 + ((ks * 32 + hl16) ^ rswz));
            bf16x8 kf1 = *(const bf16x8*)(kb_c + krow256 + (((ks + 4) * 32 + hl16) ^ rswz));
            sa = __builtin_amdgcn_mfma_f32_32x32x16_bf16(kf0, qf[ks], sa, 0, 0, 0);
            sb = __builtin_amdgcn_mfma_f32_32x32x16_bf16(kf1, qf[ks + 4], sb, 0, 0, 0);
        }

        float ab = arow;
        arow *= gm64i;
        bool diag = (jt == itile);

        // ---- half 0: decay+mask regs 0..7, pack P0 ----
        float v0[8];
        if (diag) {
            #pragma unroll
            for (int r = 0; r < 8; ++r) {
                float vv = (sa[r] + sb[r]) * (colfac[r] * ab);
                v0[r] = ((mbits >> r) & 1) ? vv : 0.0f;
            }
        } else {
            #pragma unroll
            for (int r = 0; r < 8; ++r)
                v0[r] = (sa[r] + sb[r]) * (colfac[r] * ab);
        }
        union { bf16x8 v; __bf16 e[8]; } P0;
        #pragma unroll
        for (int e = 0; e < 8; ++e) P0.e[e] = (__bf16)v0[e];

        // ---- PV half 0 (MFMA pipe; overlaps half-1 VALU below) ----
        #pragma unroll
        for (int nt = 0; nt < 4; ++nt) {
            bf16x8 vb0 = *(const bf16x8*)(vb_c + (nt * 32 + il) * 128
                                          + ((kh * 64 + hl16) ^ rswz));
            o[nt] = __builtin_amdgcn_mfma_f32_32x32x16_bf16(P0.v, vb0, o[nt], 0, 0, 0);
        }
        rowsum += ((v0[0] + v0[1]) + (v0[2] + v0[3]))
                + ((v0[4] + v0[5]) + (v0[6] + v0[7]));

        // ---- half 1: decay+mask regs 8..15, pack P1 ----
        float v1[8];
        if (diag) {
            #pragma unroll
            for (int r = 0; r < 8; ++r) {
                float vv = (sa[r + 8] + sb[r + 8]) * (colfac[r + 8] * ab);
                v1[r] = ((mbits >> (r + 8)) & 1) ? vv : 0.0f;
            }
        } else {
            #pragma unroll
            for (int r = 0; r < 8; ++r)
                v1[r] = (sa[r + 8] + sb[r + 8]) * (colfac[r + 8] * ab);
        }
        union { bf16x8 v; __bf16 e[8]; } P1;
        #pragma unroll
        for (int e = 0; e < 8; ++e) P1.e[e] = (__bf16)v1[e];

        // ---- PV half 1 ----
        #pragma unroll
        for (int nt = 0; nt < 4; ++nt) {
            bf16x8 vb1 = *(const bf16x8*)(vb_c + (nt * 32 + il) * 128
                                          + ((kh * 64 + 32 + hl16) ^ rswz));
            o[nt] = __builtin_amdgcn_mfma_f32_32x32x16_bf16(P1.v, vb1, o[nt], 0, 0, 0);
        }
        rowsum += ((v1[0] + v1[1]) + (v1[2] + v1[3]))
                + ((v1[4] + v1[5]) + (v1[6] + v1[7]));

        asm volatile("s_barrier" ::: "memory");   // readers done before overwrite
        cur ^= 1;
    }

    // ---- rowsum: combine hl halves (each holds 16 of the wave's 32 j's) ----
    float rsw = rowsum + __shfl_xor(rowsum, 32);

    // ---- cross-kh reduction via LDS (buffers dead now) ----
    __syncthreads();   // all tile reads done before buffer reuse
    float* exch = (float*)&kbuf[0][0];       // 32 KB: rh pairs at +rh*4096 floats
    float* rsx  = (float*)&vbuf[0][0];
    if (kh == 1) {
        float* eb = exch + rh * 4096;
        #pragma unroll
        for (int nt = 0; nt < 4; ++nt)
            #pragma unroll
            for (int qq = 0; qq < 4; ++qq) {
                float4 vv = { o[nt][4*qq+0], o[nt][4*qq+1],
                              o[nt][4*qq+2], o[nt][4*qq+3] };
                *(float4*)(eb + (nt * 4 + qq) * 256 + lane * 4) = vv;
            }
        if (lane < 32) rsx[rh * 32 + lane] = rsw;
    }
    __syncthreads();
    if (kh == 0) {
        float* eb = exch + rh * 4096;
        #pragma unroll
        for (int nt = 0; nt < 4; ++nt)
            #pragma unroll
            for (int qq = 0; qq < 4; ++qq) {
                float4 pv = *(const float4*)(eb + (nt * 4 + qq) * 256 + lane * 4);
                o[nt][4*qq+0] += pv.x; o[nt][4*qq+1] += pv.y;
                o[nt][4*qq+2] += pv.z; o[nt][4*qq+3] += pv.w;
            }
        float rtot = rsw + rsx[rh * 32 + il];
        float dnl = 1.0f / fmaxf(1.0f, fabsf(rtot));   // lane L&31 holds row L&31

        #pragma unroll
        for (int r = 0; r < 16; ++r) {
            int isrc = (r & 3) + 8 * (r >> 2) + 4 * hl;   // i_local of reg r
            float dn = __shfl(dnl, isrc);
            float ov[4];
            float ss = 0.0f;
            #pragma unroll
            for (int nt = 0; nt < 4; ++nt) { ov[nt] = o[nt][r] * dn; ss += ov[nt] * ov[nt]; }
            ss += __shfl_xor(ss, 1);
            ss += __shfl_xor(ss, 2);
            ss += __shfl_xor(ss, 4);
            ss += __shfl_xor(ss, 8);
            ss += __shfl_xor(ss, 16);
            float sc = rsqrtf(ss * (1.0f / 128.0f) + 1e-6f);
            int i_abs = i_base + isrc;
            float* op = out + (((size_t)b * L_ + i_abs) * H_ + h) * DV_ + il;
            #pragma unroll
            for (int nt = 0; nt < 4; ++nt) op[nt * 32] = ov[nt] * sc;
        }
    }
}

// ---- fp32 fixup for row i=0 (single-term row: eps-magnified bf16 error) ----
__global__ void fix_row0_kernel(const float* __restrict__ q,
                                const float* __restrict__ k,
                                const float* __restrict__ v,
                                float* __restrict__ out) {
    int bh = blockIdx.x;            // 0..31
    int lane = threadIdx.x;         // 0..63
    const float* qp = q + (size_t)bh * L_ * DK_;
    const float* kp = k + (size_t)bh * L_ * DK_;
    const float* vp = v + (size_t)bh * L_ * DV_;
    float part = qp[lane] * kp[lane] + qp[lane + 64] * kp[lane + 64];
    #pragma unroll
    for (int mm = 1; mm < 64; mm <<= 1) part += __shfl_xor(part, mm);
    float r00 = part;
    float cf = r00 / fmaxf(1.0f, fabsf(r00));
    float o0 = cf * vp[lane], o1 = cf * vp[lane + 64];
    float ss = o0 * o0 + o1 * o1;
    #pragma unroll
    for (int mm = 1; mm < 64; mm <<= 1) ss += __shfl_xor(ss, mm);
    float sc = rsqrtf(ss * (1.0f / 128.0f) + 1e-6f);
    int b = bh >> 4, h = bh & 15;
    float* op = out + ((size_t)b * L_ * H_ + h) * DV_;   // i = 0
    op[lane] = o0 * sc;
    op[lane + 64] = o1 * sc;
}

extern "C" void kernel_launch(void* const* d_in, const int* in_sizes, int n_in,
                              void* d_out, int out_size, void* d_ws, size_t ws_size,
                              hipStream_t stream) {
    const float* q = (const float*)d_in[0];
    const float* k = (const float*)d_in[1];
    const float* v = (const float*)d_in[2];
    // d_in[3] decay_mask (256MB) and d_in[4] intra_decay are recomputed on the fly
    float* out = (float*)d_out;

    unsigned short* kb = (unsigned short*)d_ws;                 // 16 MB
    unsigned short* vt = kb + (size_t)B_ * H_ * L_ * DK_;       // 16 MB

    prep_kernel<<<2048, 256, 0, stream>>>(k, kb, v, vt);
    retention_kernel<<<B_ * H_ * NIT, 256, 0, stream>>>(q, kb, vt, out);
    fix_row0_kernel<<<B_ * H_, 64, 0, stream>>>(q, k, v, out);
}

// Round 10
// 84.002 us; speedup vs baseline: 1.1478x; 1.0592x over previous
//
#include <hip/hip_runtime.h>
#include <hip/hip_bf16.h>
#include <math.h>

// SelfRetentionV1: B=2,H=16,L=2048,DK=128,DV=128
// out[b,l,h,d] = RMSNorm_d( (QK^T * gamma^(i-j) / max(1,|rowsum|)) @ V )
#define B_ 2
#define H_ 16
#define L_ 2048
#define DK_ 128
#define DV_ 128
#define QBLK 64
#define KVBLK 64
#define NIT (L_/KVBLK)   // 32

typedef __bf16 bf16x8 __attribute__((ext_vector_type(8)));
typedef float  f32x16 __attribute__((ext_vector_type(16)));

static __device__ __forceinline__ unsigned short f2bf(float f) {
    union { float f; unsigned int u; } x; x.f = f;
    unsigned int r = x.u + 0x7fffu + ((x.u >> 16) & 1u);  // RNE
    return (unsigned short)(r >> 16);
}

// async global->LDS, 16B per lane; LDS dest = wave-uniform base + lane*16
static __device__ __forceinline__ void gload_lds16(const void* g, void* l) {
    __builtin_amdgcn_global_load_lds(
        (const __attribute__((address_space(1))) unsigned int*)g,
        (__attribute__((address_space(3))) unsigned int*)l,
        16, 0, 0);
}

// K tile rows are 256B: swizzle bits 4-6 by row&7 (involution, row bits >=8)
#define KSWZ(d) ((d) ^ ((((d) >> 8) & 7) << 4))
// V tile rows are 128B: row bits >=7
#define VSWZ(d) ((d) ^ ((((d) >> 7) & 7) << 4))

// ---- fused pre-pass: blocks 0..1023 convert K fp32->bf16;
//      blocks 1024..2047 transpose V -> VT[bh][dv][perm(l)] (bit2<->3 perm
//      so P-register order == mfma k-slot order in PV) ----
__global__ void prep_kernel(const float* __restrict__ kin,
                            unsigned short* __restrict__ kb,
                            const float* __restrict__ v,
                            unsigned short* __restrict__ vt) {
    __shared__ unsigned short lds[64][130];   // +2 pad (transpose half only)
    int bid = blockIdx.x;
    if (bid < 1024) {
        int n4 = B_ * H_ * L_ * DK_ / 4;
        int i = bid * 256 + threadIdx.x;
        int stride = 1024 * 256;
        for (; i < n4; i += stride) {
            float4 f = ((const float4*)kin)[i];
            uint2 o;
            o.x = (unsigned)f2bf(f.x) | ((unsigned)f2bf(f.y) << 16);
            o.y = (unsigned)f2bf(f.z) | ((unsigned)f2bf(f.w) << 16);
            ((uint2*)kb)[i] = o;
        }
        return;
    }
    int blk = bid - 1024;
    int ltile = blk & (L_/64 - 1);
    int bh = blk / (L_/64);
    const float* vp = v + ((size_t)bh * L_ + (size_t)ltile * 64) * DV_;
    unsigned short* vo = vt + (size_t)bh * DV_ * L_ + ltile * 64;
    int t = threadIdx.x;
    int r0 = t >> 5, c0 = (t & 31) * 4;
    #pragma unroll
    for (int it = 0; it < 8; ++it) {
        int row = r0 + 8 * it;
        float4 f = *(const float4*)(vp + row * DV_ + c0);
        lds[row][c0 + 0] = f2bf(f.x);
        lds[row][c0 + 1] = f2bf(f.y);
        lds[row][c0 + 2] = f2bf(f.z);
        lds[row][c0 + 3] = f2bf(f.w);
    }
    __syncthreads();
    int dvb = t >> 3, seg = t & 7;
    #pragma unroll
    for (int ot = 0; ot < 4; ++ot) {
        int dv = dvb + 32 * ot;
        unsigned short a[8];
        #pragma unroll
        for (int tt = 0; tt < 8; ++tt) {
            int pp = seg * 8 + tt;
            int js = (pp & ~12) | ((pp & 4) << 1) | ((pp & 8) >> 1);  // swap b2,b3
            a[tt] = lds[js][dv];
        }
        uint4 st;
        st.x = (unsigned)a[0] | ((unsigned)a[1] << 16);
        st.y = (unsigned)a[2] | ((unsigned)a[3] << 16);
        st.z = (unsigned)a[4] | ((unsigned)a[5] << 16);
        st.w = (unsigned)a[6] | ((unsigned)a[7] << 16);
        *(uint4*)(vo + (size_t)dv * L_ + seg * 8) = st;
    }
}

// ---- main kernel: 4 waves (rh,kh); swapped QK^T, register P.
// LOAD-BALANCED: each block processes TWO q-tiles sequentially,
// itile = s and 31-s, so EVERY block is exactly 33 rounds. Grid = 512 =
// exact residency capacity (2 blocks/CU): every CU runs 2 co-resident
// 33-round blocks for the whole kernel -- no single-block latency tail
// (the old 1024-grid paired equal-length blocks into the same residency
// stream: CU 0/31 ran 64 SEQUENTIAL rounds with 1 resident block).
// Round body = proven r9 structure: K/V dbuf, stage-at-top, vmcnt(8),
// 2 s_barrier/round, split QK chains, PV interleaved with decay halves.
__launch_bounds__(256, 2)
__global__ void retention_kernel(const float* __restrict__ q,
                                 const unsigned short* __restrict__ kb,
                                 const unsigned short* __restrict__ vt_,
                                 float* __restrict__ out) {
    __shared__ __align__(16) unsigned short kbuf[2][64 * 128];   // 32 KB
    __shared__ __align__(16) unsigned short vbuf[2][128 * 64];   // 32 KB

    // bh->XCD-pinned remap (xcd = bid%8): 4 bh per XCD -> ~4MB K+V ~= L2
    int bid = blockIdx.x;            // 0..511
    int x   = bid & 7;               // XCD id
    int t_  = bid >> 3;              // 0..63
    int hi  = t_ >> 4;               // 0..3
    int sp  = t_ & 15;               // 0..15: q-tile pair (sp, 31-sp)
    int bh = hi * 8 + x;
    int b = bh >> 4, h = bh & 15;

    int tid = threadIdx.x;
    int lane = tid & 63;
    int w = tid >> 6;                   // 0..3
    int rh = w >> 1;                    // q-row half
    int kh = w & 1;                     // kv half
    int il = lane & 31;
    int hl = lane >> 5;

    const unsigned short* kbp = kb  + (size_t)bh * L_ * DK_;
    const unsigned short* vtp = vt_ + (size_t)bh * DV_ * L_;

    // hoisted per-lane stage offsets (loop-invariant)
    int dwv[4], koff[4], voff[4];
    #pragma unroll
    for (int is = 0; is < 4; ++is) {
        int dw = is * 4096 + w * 1024;
        int d  = dw + lane * 16;
        dwv[is]  = dw;
        koff[is] = KSWZ(d);
        int sv   = VSWZ(d);
        voff[is] = (sv >> 7) * (L_ * 2) + (sv & 127);
    }

    float ex = exp2f((float)(-5 - h));
    float gamma = 1.0f - ex;
    float log2g = log1pf(-ex) * 1.44269504088896f;

    // colfac[r] = gamma^(-jr), jr = (r&3) + 8*(r>>2) + 4*hl
    float gi  = exp2f(-log2g);
    float gi2 = gi * gi, gi3 = gi2 * gi, gi4 = gi2 * gi2;
    float gi8 = gi4 * gi4, gi16 = gi8 * gi8, gi24 = gi16 * gi8;
    float cfq[4] = {1.f, gi, gi2, gi3};
    float cfp[4] = {1.f, gi8, gi16, gi24};
    float chl = hl ? gi4 : 1.f;
    float colfac[16];
    #pragma unroll
    for (int r = 0; r < 16; ++r) colfac[r] = cfq[r & 3] * cfp[r >> 2] * chl;

    float gm64i = exp2f(log2g * (-64.0f));
    int icmp = rh * 32 + il - kh * 32;   // diag mask: jr <= icmp (seg-invariant)
    unsigned mbits = 0;                  // bit r: keep reg r on diagonal tile
    #pragma unroll
    for (int r = 0; r < 16; ++r)
        if (((r & 3) + 8 * (r >> 2) + 4 * hl) <= icmp) mbits |= 1u << r;

    int rswz = (il & 7) << 4;           // read-side XOR (rows == il mod 8)
    int krow256 = (kh * 32 + il) * 256;
    int hl16 = hl * 16;

    for (int seg = 0; seg < 2; ++seg) {
        int itile = seg ? (31 - sp) : sp;
        int i_base = itile * QBLK + rh * 32;
        int i_row  = i_base + il;       // this lane's q-row

        // ---- stage tile 0 of this segment (DMA runs under setup below) ----
        {
            const char* ksrc = (const char*)kbp;
            const char* vsrc = (const char*)vtp;
            #pragma unroll
            for (int is = 0; is < 4; ++is) {
                gload_lds16(ksrc + koff[is], (char*)&kbuf[0][0] + dwv[is]);
                gload_lds16(vsrc + voff[is], (char*)&vbuf[0][0] + dwv[is]);
            }
        }

        // arow = gamma^(i - jt*64 - kh*32), advanced by *= gamma^-64 per tile
        float arow = exp2f(log2g * (float)(i_row - kh * 32));

        // Q as B-operand: col = il (q-row i_row), k = ks*16 + hl*8 + 0..7
        bf16x8 qf[8];
        {
            const float* qp = q + ((size_t)bh * L_ + i_row) * DK_ + hl * 8;
            #pragma unroll
            for (int ks = 0; ks < 8; ++ks) {
                float4 f0 = *(const float4*)(qp + ks * 16);
                float4 f1 = *(const float4*)(qp + ks * 16 + 4);
                union { bf16x8 v; unsigned short u[8]; } A;
                A.u[0]=f2bf(f0.x); A.u[1]=f2bf(f0.y); A.u[2]=f2bf(f0.z); A.u[3]=f2bf(f0.w);
                A.u[4]=f2bf(f1.x); A.u[5]=f2bf(f1.y); A.u[6]=f2bf(f1.z); A.u[7]=f2bf(f1.w);
                qf[ks] = A.v;
            }
        }

        f32x16 o[4];                    // O^T: lane = dv (il), regs = i-pattern
        #pragma unroll
        for (int nt = 0; nt < 4; ++nt)
            #pragma unroll
            for (int e = 0; e < 16; ++e) o[nt][e] = 0.0f;
        float rowsum = 0.0f;

        int cur = 0;
        for (int jt = 0; jt <= itile; ++jt) {
            // issue next stage, then wait for PREVIOUS stage only (counted)
            if (jt < itile) {
                const char* ksrc = (const char*)(kbp + (size_t)(jt + 1) * KVBLK * DK_);
                const char* vsrc = (const char*)(vtp + (jt + 1) * KVBLK);
                char* kdst = (char*)&kbuf[cur ^ 1][0];
                char* vdst = (char*)&vbuf[cur ^ 1][0];
                #pragma unroll
                for (int is = 0; is < 4; ++is) {
                    gload_lds16(ksrc + koff[is], kdst + dwv[is]);
                    gload_lds16(vsrc + voff[is], vdst + dwv[is]);
                }
                asm volatile("s_waitcnt vmcnt(8)" ::: "memory");
            } else {
                asm volatile("s_waitcnt vmcnt(0)" ::: "memory");
            }
            asm volatile("s_barrier" ::: "memory");   // stage(jt) landed

            const char* kb_c = (const char*)&kbuf[cur][0];
            const char* vb_c = (const char*)&vbuf[cur][0];

            // ---- S^T = mfma(K, Q): TWO independent 4-deep chains ----
            f32x16 sa, sb;
            #pragma unroll
            for (int e = 0; e < 16; ++e) { sa[e] = 0.0f; sb[e] = 0.0f; }
            #pragma unroll
            for (int ks = 0; ks < 4; ++ks) {
                bf16x8 kf0 = *(const bf16x8*)(kb_c + krow256 + ((ks * 32 + hl16) ^ rswz));
                bf16x8 kf1 = *(const bf16x8*)(kb_c + krow256 + (((ks + 4) * 32 + hl16) ^ rswz));
                sa = __builtin_amdgcn_mfma_f32_32x32x16_bf16(kf0, qf[ks], sa, 0, 0, 0);
                sb = __builtin_amdgcn_mfma_f32_32x32x16_bf16(kf1, qf[ks + 4], sb, 0, 0, 0);
            }

            float ab = arow;
            arow *= gm64i;
            bool diag = (jt == itile);

            // ---- half 0: decay+mask regs 0..7, pack P0 ----
            float v0[8];
            if (diag) {
                #pragma unroll
                for (int r = 0; r < 8; ++r) {
                    float vv = (sa[r] + sb[r]) * (colfac[r] * ab);
                    v0[r] = ((mbits >> r) & 1) ? vv : 0.0f;
                }
            } else {
                #pragma unroll
                for (int r = 0; r < 8; ++r)
                    v0[r] = (sa[r] + sb[r]) * (colfac[r] * ab);
            }
            union { bf16x8 v; __bf16 e[8]; } P0;
            #pragma unroll
            for (int e = 0; e < 8; ++e) P0.e[e] = (__bf16)v0[e];

            // ---- PV half 0 (MFMA pipe; overlaps half-1 VALU below) ----
            #pragma unroll
            for (int nt = 0; nt < 4; ++nt) {
                bf16x8 vb0 = *(const bf16x8*)(vb_c + (nt * 32 + il) * 128
                                              + ((kh * 64 + hl16) ^ rswz));
                o[nt] = __builtin_amdgcn_mfma_f32_32x32x16_bf16(P0.v, vb0, o[nt], 0, 0, 0);
            }
            rowsum += ((v0[0] + v0[1]) + (v0[2] + v0[3]))
                    + ((v0[4] + v0[5]) + (v0[6] + v0[7]));

            // ---- half 1: decay+mask regs 8..15, pack P1 ----
            float v1[8];
            if (diag) {
                #pragma unroll
                for (int r = 0; r < 8; ++r) {
                    float vv = (sa[r + 8] + sb[r + 8]) * (colfac[r + 8] * ab);
                    v1[r] = ((mbits >> (r + 8)) & 1) ? vv : 0.0f;
                }
            } else {
                #pragma unroll
                for (int r = 0; r < 8; ++r)
                    v1[r] = (sa[r + 8] + sb[r + 8]) * (colfac[r + 8] * ab);
            }
            union { bf16x8 v; __bf16 e[8]; } P1;
            #pragma unroll
            for (int e = 0; e < 8; ++e) P1.e[e] = (__bf16)v1[e];

            // ---- PV half 1 ----
            #pragma unroll
            for (int nt = 0; nt < 4; ++nt) {
                bf16x8 vb1 = *(const bf16x8*)(vb_c + (nt * 32 + il) * 128
                                              + ((kh * 64 + 32 + hl16) ^ rswz));
                o[nt] = __builtin_amdgcn_mfma_f32_32x32x16_bf16(P1.v, vb1, o[nt], 0, 0, 0);
            }
            rowsum += ((v1[0] + v1[1]) + (v1[2] + v1[3]))
                    + ((v1[4] + v1[5]) + (v1[6] + v1[7]));

            asm volatile("s_barrier" ::: "memory");   // readers done pre-overwrite
            cur ^= 1;
        }

        // ---- rowsum: combine hl halves ----
        float rsw = rowsum + __shfl_xor(rowsum, 32);

        // ---- cross-kh reduction via LDS (tile buffers dead now) ----
        __syncthreads();   // all tile reads done before buffer reuse
        float* exch = (float*)&kbuf[0][0];   // rh pairs at +rh*4096 floats
        float* rsx  = (float*)&vbuf[0][0];
        if (kh == 1) {
            float* eb = exch + rh * 4096;
            #pragma unroll
            for (int nt = 0; nt < 4; ++nt)
                #pragma unroll
                for (int qq = 0; qq < 4; ++qq) {
                    float4 vv = { o[nt][4*qq+0], o[nt][4*qq+1],
                                  o[nt][4*qq+2], o[nt][4*qq+3] };
                    *(float4*)(eb + (nt * 4 + qq) * 256 + lane * 4) = vv;
                }
            if (lane < 32) rsx[rh * 32 + lane] = rsw;
        }
        __syncthreads();
        if (kh == 0) {
            float* eb = exch + rh * 4096;
            #pragma unroll
            for (int nt = 0; nt < 4; ++nt)
                #pragma unroll
                for (int qq = 0; qq < 4; ++qq) {
                    float4 pv = *(const float4*)(eb + (nt * 4 + qq) * 256 + lane * 4);
                    o[nt][4*qq+0] += pv.x; o[nt][4*qq+1] += pv.y;
                    o[nt][4*qq+2] += pv.z; o[nt][4*qq+3] += pv.w;
                }
            float rtot = rsw + rsx[rh * 32 + il];
            float dnl = 1.0f / fmaxf(1.0f, fabsf(rtot));

            #pragma unroll
            for (int r = 0; r < 16; ++r) {
                int isrc = (r & 3) + 8 * (r >> 2) + 4 * hl;   // i_local of reg r
                float dn = __shfl(dnl, isrc);
                float ov[4];
                float ss = 0.0f;
                #pragma unroll
                for (int nt = 0; nt < 4; ++nt) { ov[nt] = o[nt][r] * dn; ss += ov[nt] * ov[nt]; }
                ss += __shfl_xor(ss, 1);
                ss += __shfl_xor(ss, 2);
                ss += __shfl_xor(ss, 4);
                ss += __shfl_xor(ss, 8);
                ss += __shfl_xor(ss, 16);
                float sc = rsqrtf(ss * (1.0f / 128.0f) + 1e-6f);
                int i_abs = i_base + isrc;
                float* op = out + (((size_t)b * L_ + i_abs) * H_ + h) * DV_ + il;
                #pragma unroll
                for (int nt = 0; nt < 4; ++nt) op[nt * 32] = ov[nt] * sc;
            }
        }
        __syncthreads();   // exch reads done before next segment's staging
    }
}

// ---- fp32 fixup for row i=0 (single-term row: eps-magnified bf16 error) ----
__global__ void fix_row0_kernel(const float* __restrict__ q,
                                const float* __restrict__ k,
                                const float* __restrict__ v,
                                float* __restrict__ out) {
    int bh = blockIdx.x;            // 0..31
    int lane = threadIdx.x;         // 0..63
    const float* qp = q + (size_t)bh * L_ * DK_;
    const float* kp = k + (size_t)bh * L_ * DK_;
    const float* vp = v + (size_t)bh * L_ * DV_;
    float part = qp[lane] * kp[lane] + qp[lane + 64] * kp[lane + 64];
    #pragma unroll
    for (int mm = 1; mm < 64; mm <<= 1) part += __shfl_xor(part, mm);
    float r00 = part;
    float cf = r00 / fmaxf(1.0f, fabsf(r00));
    float o0 = cf * vp[lane], o1 = cf * vp[lane + 64];
    float ss = o0 * o0 + o1 * o1;
    #pragma unroll
    for (int mm = 1; mm < 64; mm <<= 1) ss += __shfl_xor(ss, mm);
    float sc = rsqrtf(ss * (1.0f / 128.0f) + 1e-6f);
    int b = bh >> 4, h = bh & 15;
    float* op = out + ((size_t)b * L_ * H_ + h) * DV_;   // i = 0
    op[lane] = o0 * sc;
    op[lane + 64] = o1 * sc;
}

extern "C" void kernel_launch(void* const* d_in, const int* in_sizes, int n_in,
                              void* d_out, int out_size, void* d_ws, size_t ws_size,
                              hipStream_t stream) {
    const float* q = (const float*)d_in[0];
    const float* k = (const float*)d_in[1];
    const float* v = (const float*)d_in[2];
    // d_in[3] decay_mask (256MB) and d_in[4] intra_decay are recomputed on the fly
    float* out = (float*)d_out;

    unsigned short* kb = (unsigned short*)d_ws;                 // 16 MB
    unsigned short* vt = kb + (size_t)B_ * H_ * L_ * DK_;       // 16 MB

    prep_kernel<<<2048, 256, 0, stream>>>(k, kb, v, vt);
    retention_kernel<<<512, 256, 0, stream>>>(q, kb, vt, out);
    fix_row0_kernel<<<B_ * H_, 64, 0, stream>>>(q, k, v, out);
}